// Round 3
// baseline (1089.838 us; speedup 1.0000x reference)
//
#include <hip/hip_runtime.h>
#include <math.h>

// Text2SemanticDecoder single-token decode, MI355X round 4.
// R3 (619us decode): contention-free 2-hop barrier; still latency-bound
// (HBM 6.7%, VALU 2.7%) — every stage paid cold DRAM latency for weights
// plus ~3us two-hop barrier. R4:
//  (a) one-hop all-to-all barrier: arr[blk]=epoch, every block's thread t
//      polls arr[t] (1 store, 256 independent pollers/slot, no RMW chain).
//  (b) weight prefetch: global_load_lds (16B) issues next-stage weight
//      slices into LDS at stage start; loads fly under compute+barrier;
//      the barrier's vmcnt(0) drain guarantees readiness. Pipeline:
//      st1->KV, st2->outw+ff1, st3->ff2, st4->qkvw(l+1). LDS ~133KB/CU.
//  (c) QK^T restructured PV-style (lane=d, shfl-reduce) -> bank-conflict-free.

#define LNUM 24
#define TPOS 2048
#define DMOD 512
#define HNUM 16
#define VOC  1025
#define TYN  512
#define FFD  2048
#define DHD  32
#define NBLK 256
#define NTHR 256

#define INV_SQRT_DH 0.17677669529663687f

// ---------------- helpers ----------------

__device__ __forceinline__ unsigned rotl32(unsigned x, int d) {
    return (x << d) | (x >> (32 - d));
}

// threefry2x32, PARTITIONABLE scheme: key=(0,42), ctr=(0,i), bits=o0^o1
__device__ float threefry_normal(int i) {
    unsigned c0 = 0u;
    unsigned c1 = (unsigned)i;
    unsigned ks[3];
    ks[0] = 0u; ks[1] = 42u; ks[2] = 0x1BD11BDAu ^ ks[0] ^ ks[1];
    unsigned x0 = c0 + ks[0];
    unsigned x1 = c1 + ks[1];
    const int r0[4] = {13, 15, 26, 6};
    const int r1[4] = {17, 29, 16, 24};
    #pragma unroll
    for (int g = 0; g < 5; ++g) {
        const int* rr = (g & 1) ? r1 : r0;
        #pragma unroll
        for (int j = 0; j < 4; ++j) {
            x0 += x1; x1 = rotl32(x1, rr[j]); x1 ^= x0;
        }
        x0 += ks[(g + 1) % 3];
        x1 += ks[(g + 2) % 3] + (unsigned)(g + 1);
    }
    unsigned bits = x0 ^ x1;
    float u01 = __uint_as_float((bits >> 9) | 0x3f800000u) - 1.0f;
    const float lo = -0.99999994f;
    float u = u01 * (1.0f - lo) + lo;
    u = fmaxf(lo, u);
    float w = -log1pf(-u * u);
    float pp;
    if (w < 5.0f) {
        w = w - 2.5f;
        pp = 2.81022636e-08f;
        pp = fmaf(pp, w, 3.43273939e-07f);
        pp = fmaf(pp, w, -3.5233877e-06f);
        pp = fmaf(pp, w, -4.39150654e-06f);
        pp = fmaf(pp, w, 0.00021858087f);
        pp = fmaf(pp, w, -0.00125372503f);
        pp = fmaf(pp, w, -0.00417768164f);
        pp = fmaf(pp, w, 0.246640727f);
        pp = fmaf(pp, w, 1.50140941f);
    } else {
        w = sqrtf(w) - 3.0f;
        pp = -0.000200214257f;
        pp = fmaf(pp, w, 0.000100950558f);
        pp = fmaf(pp, w, 0.00134934322f);
        pp = fmaf(pp, w, -0.00367342844f);
        pp = fmaf(pp, w, 0.00573950773f);
        pp = fmaf(pp, w, -0.0076224613f);
        pp = fmaf(pp, w, 0.00943887047f);
        pp = fmaf(pp, w, 1.00167406f);
        pp = fmaf(pp, w, 2.83297682f);
    }
    return 1.4142135623730951f * pp * u;  // sqrt(2)*erfinv(u)
}

__global__ void zero_kernel(float* p, int n) {
    int i = blockIdx.x * blockDim.x + threadIdx.x;
    if (i < n) p[i] = 0.0f;
}

__device__ __forceinline__ float wave_red_sum(float v) {
    #pragma unroll
    for (int o = 32; o; o >>= 1) v += __shfl_xor(v, o, 64);
    return v;
}
__device__ __forceinline__ float wave_red_max(float v) {
    #pragma unroll
    for (int o = 32; o; o >>= 1) v = fmaxf(v, __shfl_xor(v, o, 64));
    return v;
}
__device__ __forceinline__ float block_sum(float v, float* red8, int tid) {
    v = wave_red_sum(v);
    __syncthreads();
    if ((tid & 63) == 0) red8[tid >> 6] = v;
    __syncthreads();
    return red8[0] + red8[1] + red8[2] + red8[3];
}
__device__ __forceinline__ float block_max(float v, float* red8, int tid) {
    v = wave_red_max(v);
    __syncthreads();
    if ((tid & 63) == 0) red8[tid >> 6] = v;
    __syncthreads();
    return fmaxf(fmaxf(red8[0], red8[1]), fmaxf(red8[2], red8[3]));
}

// agent-scope (cross-XCD coherent) load/store for small intermediates
__device__ __forceinline__ float gloadf(const float* p) {
    return __hip_atomic_load((float*)p, __ATOMIC_RELAXED, __HIP_MEMORY_SCOPE_AGENT);
}
__device__ __forceinline__ void gstoref(float* p, float v) {
    __hip_atomic_store(p, v, __ATOMIC_RELAXED, __HIP_MEMORY_SCOPE_AGENT);
}

// async global->LDS, 16B per lane. lds base must be wave-uniform; HW writes
// each lane's 16B at base + lane*16.
__device__ __forceinline__ void gl_lds16(const float* g, float* l) {
    __builtin_amdgcn_global_load_lds(
        (const __attribute__((address_space(1))) unsigned int*)g,
        (__attribute__((address_space(3))) unsigned int*)l, 16, 0, 0);
}

// One-hop all-to-all grid barrier: block stores arr[blk]=epoch; thread t of
// EVERY block polls arr[t]. Loads don't serialize (unlike RMW). The entry
// __syncthreads drains vmcnt (compiler emits s_waitcnt vmcnt(0) before
// s_barrier), providing release for all prior global writes & prefetches.
__device__ __forceinline__ void gsync(volatile unsigned* arr, unsigned& epoch,
                                      int tid, int blk) {
    __syncthreads();               // all waves' vmem (incl. global_load_lds) drained
    ++epoch;
    if (tid == 0)
        __hip_atomic_store((unsigned*)&arr[blk * 16], epoch, __ATOMIC_RELAXED,
                           __HIP_MEMORY_SCOPE_AGENT);
    while (__hip_atomic_load((unsigned*)&arr[tid * 16], __ATOMIC_RELAXED,
                             __HIP_MEMORY_SCOPE_AGENT) < epoch)
        __builtin_amdgcn_s_sleep(1);
    __syncthreads();
}

// LN(u) -> xs[512] in LDS; u is a cross-stage intermediate (agent loads).
__device__ __forceinline__ void ln_into(const float* __restrict__ u, const float* __restrict__ g,
                                        const float* __restrict__ b, float* xs, float* red8, int tid) {
    float a = gloadf(u + tid), c = gloadf(u + tid + 256);
    float s1 = block_sum(a + c, red8, tid);
    float s2 = block_sum(a * a + c * c, red8, tid);
    float mu = s1 * (1.0f / DMOD);
    float var = s2 * (1.0f / DMOD) - mu * mu;
    float rstd = rsqrtf(var + 1e-5f);
    xs[tid]       = (a - mu) * rstd * g[tid] + b[tid];
    xs[tid + 256] = (c - mu) * rstd * g[tid + 256] + b[tid + 256];
    __syncthreads();
}

// layer-0 input: tok_emb[last] + alpha*pe(pos=512)
__device__ __forceinline__ void x0_into(const int* __restrict__ y, const float* __restrict__ tokemb,
                                        const float* __restrict__ alpha, float* xs, int tid) {
    int tok = y[TYN - 1];
    #pragma unroll
    for (int r = 0; r < 2; ++r) {
        int d = tid + r * 256;
        float e = tokemb[(size_t)tok * DMOD + d];
        int base = d & ~1;
        float div = expf(-(float)base * (logf(10000.0f) / (float)DMOD));
        float ang = 512.0f * div;
        float pe = (d & 1) ? cosf(ang) : sinf(ang);
        xs[d] = e + alpha[0] * pe;
    }
    __syncthreads();
}

// ---------------- the persistent kernel ----------------

__global__ __launch_bounds__(NTHR) void decode_kernel(
    const int* __restrict__ y, const float* __restrict__ kcache, const float* __restrict__ vcache,
    const float* __restrict__ tokemb, const float* __restrict__ alpha,
    const float* __restrict__ qkvw, const float* __restrict__ qkvbias,
    const float* __restrict__ outw, const float* __restrict__ outb,
    const float* __restrict__ ln1g, const float* __restrict__ ln1b,
    const float* __restrict__ ff1w, const float* __restrict__ ff1b,
    const float* __restrict__ ff2w, const float* __restrict__ ff2b,
    const float* __restrict__ ln2g, const float* __restrict__ ln2b,
    const float* __restrict__ predw, float* __restrict__ out, float* ws)
{
    // weight staging buffers (prefetch pipeline)
    __shared__ float qw_lds[4096];      // 32 rows x 128 cols   (stage 1)
    __shared__ float kv_lds[8192];      // K[128][32] | V[128][32] (stage 2)
    __shared__ float ow_lds[1024];      // 32 x 32              (stage 3)
    __shared__ float f1_lds[8192];      // 512 x 16             (stage 4)
    __shared__ float f2_lds[8192];      // 16 x 512             (stage 4)
    // small scratch
    __shared__ float xs[DMOD];
    __shared__ float red8[8];
    __shared__ float ps[136];           // 129 scores
    __shared__ float vred[NTHR];
    __shared__ float qs[DHD];
    __shared__ float os[DHD];
    __shared__ float hs[16];
    __shared__ float redt[NTHR];
    // final stage
    __shared__ float lg[VOC];
    __shared__ float sel[VOC];
    __shared__ unsigned char flagc[VOC];
    __shared__ float rv[4];
    __shared__ int   ri[4];

    int tid = threadIdx.x, blk = blockIdx.x;
    int wave = tid >> 6;

    // ws layout (floats):
    //   [0,4096)   arrive slots (256 x 16-word stride)
    //   [4096,..)  qkv[24*1536] | u1[24*512] | u2[24*512] | attnp[16*16*34] | logits[1025]
    volatile unsigned* arr = (volatile unsigned*)ws;
    float* qkv_all  = ws + 4096;
    float* u1_all   = qkv_all + LNUM * 3 * DMOD;
    float* u2_all   = u1_all + LNUM * DMOD;
    float* attnp    = u2_all + LNUM * DMOD;
    float* logits   = attnp + HNUM * 16 * 34;
    unsigned epoch  = 0;

    float* kout = out + 1026;
    float* vout = out + 1026 + (size_t)LNUM * DMOD;

    // prologue: prefetch layer-0 qkvw slice
    if (blk < 192) {
        int cb = blk >> 4, ks = blk & 15;
        const float* wb = qkvw + (size_t)(ks * 32) * (3 * DMOD) + cb * 128;
        #pragma unroll
        for (int r = 0; r < 4; ++r) {
            int f = (r * 256 + tid) * 4;
            int row = f >> 7, col = f & 127;
            gl_lds16(wb + (size_t)row * (3 * DMOD) + col, qw_lds + (r * 256 + wave * 64) * 4);
        }
    }
    __syncthreads();   // drain prologue prefetch (vmcnt)

    for (int l = 0; l < LNUM; ++l) {
        const float* u_prev = (l == 0) ? (const float*)0 : (u2_all + (size_t)(l - 1) * DMOD);
        const float* gp = (l == 0) ? (const float*)0 : (ln2g + (size_t)(l - 1) * DMOD);
        const float* bp = (l == 0) ? (const float*)0 : (ln2b + (size_t)(l - 1) * DMOD);
        float* qkvb = qkv_all + (size_t)l * 3 * DMOD;
        int h = blk >> 4, c = blk & 15;   // stage-2/3 roles

        // ---- stage 1: prefetch KV chunk; qkv = LN(x) @ W + b (192 blocks) ----
        {
            const float* kb = kcache + (size_t)l * TPOS * DMOD + (size_t)(c * 128) * DMOD + h * DHD;
            const float* vb = vcache + (size_t)l * TPOS * DMOD + (size_t)(c * 128) * DMOD + h * DHD;
            #pragma unroll
            for (int r = 0; r < 4; ++r) {
                int f = (r * 256 + tid) * 4;
                int row = f >> 5, col = f & 31;
                gl_lds16(kb + (size_t)row * DMOD + col, kv_lds + (r * 256 + wave * 64) * 4);
            }
            #pragma unroll
            for (int r = 0; r < 4; ++r) {
                int f = (r * 256 + tid) * 4;
                int row = f >> 5, col = f & 31;
                gl_lds16(vb + (size_t)row * DMOD + col, kv_lds + 4096 + (r * 256 + wave * 64) * 4);
            }
        }
        if (blk < 192) {
            if (l == 0) x0_into(y, tokemb, alpha, xs, tid);
            else        ln_into(u_prev, gp, bp, xs, red8, tid);
            int cb = blk >> 4, ks = blk & 15;
            int cc = tid & 127, rg = tid >> 7;
            int col = cb * 128 + cc;
            float acc = 0.f;
            #pragma unroll
            for (int i = 0; i < 16; ++i)
                acc += xs[ks * 32 + rg * 16 + i] * qw_lds[(rg * 16 + i) * 128 + cc];
            if (ks == 0 && tid < 128) acc += qkvbias[(size_t)l * 3 * DMOD + col];
            atomicAdd(&qkvb[col], acc);
        }
        gsync(arr, epoch, tid, blk);

        // ---- stage 2: prefetch outw + ff1; attention partials (all 256 blocks) ----
        {
            const float* ob = outw + (size_t)l * DMOD * DMOD + (size_t)(h * DHD) * DMOD + c * 32;
            {
                int f = tid * 4;
                int row = f >> 5, col = f & 31;
                gl_lds16(ob + (size_t)row * DMOD + col, ow_lds + wave * 64 * 4);
            }
            if (blk < 128) {
                const float* f1 = ff1w + (size_t)l * DMOD * FFD + blk * 16;
                #pragma unroll
                for (int r = 0; r < 8; ++r) {
                    int f = (r * 256 + tid) * 4;
                    int row = f >> 4, col = f & 15;
                    gl_lds16(f1 + (size_t)row * FFD + col, f1_lds + (r * 256 + wave * 64) * 4);
                }
            }
            // q head (data-dep)
            if (tid < DHD) qs[tid] = gloadf(&qkvb[h * DHD + tid]);
            __syncthreads();
            int d = tid & 31, pg = tid >> 5;   // 8 pos-groups
            // QK^T: lane=d, shuffle-reduce over 32 lanes (conflict-free LDS)
            #pragma unroll
            for (int it = 0; it < 16; ++it) {
                int pos = pg + it * 8;
                float prod = qs[d] * kv_lds[pos * 32 + d];
                #pragma unroll
                for (int o = 16; o; o >>= 1) prod += __shfl_xor(prod, o, 64);
                if (d == 0) ps[pos] = prod * INV_SQRT_DH;
            }
            if (c == 15 && tid < 32) {        // new token score
                float prod = qs[tid] * gloadf(&qkvb[DMOD + h * DHD + tid]);
                #pragma unroll
                for (int o = 16; o; o >>= 1) prod += __shfl_xor(prod, o, 64);
                if (tid == 0) ps[128] = prod * INV_SQRT_DH;
            }
            __syncthreads();
            int limit = (c == 15) ? 129 : 128;
            float sv = (tid < limit) ? ps[tid] : -INFINITY;
            float m = block_max(sv, red8, tid);
            float pe = expf(sv - m);
            if (tid < limit) ps[tid] = pe;
            float lsum = block_sum((tid < limit) ? pe : 0.f, red8, tid);
            // PV
            float acc = 0.f;
            #pragma unroll
            for (int it = 0; it < 16; ++it) {
                int p2 = pg + it * 8;
                acc += ps[p2] * kv_lds[4096 + p2 * 32 + d];
            }
            if (c == 15 && pg == 0) acc += ps[128] * gloadf(&qkvb[2 * DMOD + h * DHD + d]);
            vred[tid] = acc;
            __syncthreads();
            float* ap = attnp + (size_t)(h * 16 + c) * 34;
            if (tid < DHD) {
                float a = 0.f;
                #pragma unroll
                for (int g = 0; g < 8; ++g) a += vred[g * DHD + tid];
                gstoref(&ap[2 + tid], a);
            }
            if (tid == 0) { gstoref(&ap[0], m); gstoref(&ap[1], lsum); }
            if (c == 0 && tid < DHD) {
                kout[(size_t)l * DMOD + h * DHD + tid] = gloadf(&qkvb[DMOD + h * DHD + tid]);
                vout[(size_t)l * DMOD + h * DHD + tid] = gloadf(&qkvb[2 * DMOD + h * DHD + tid]);
            }
        }
        gsync(arr, epoch, tid, blk);

        // ---- stage 3: prefetch ff2; combine + out-proj + residual -> u1 ----
        {
            if (blk < 128) {
                const float* f2 = ff2w + (size_t)l * FFD * DMOD + (size_t)(blk * 16) * DMOD;
                #pragma unroll
                for (int r = 0; r < 8; ++r) {
                    int f = (r * 256 + tid) * 4;
                    gl_lds16(f2 + f, f2_lds + (r * 256 + wave * 64) * 4);
                }
            }
            if (h == 0) {
                if (l == 0) x0_into(y, tokemb, alpha, xs, tid);
                else        ln_into(u_prev, gp, bp, xs, red8, tid);
            }
            const float* apb = attnp + (size_t)(h * 16) * 34;
            if (tid < DHD) {
                float M = -INFINITY;
                #pragma unroll
                for (int cc = 0; cc < 16; ++cc) M = fmaxf(M, gloadf(&apb[cc * 34]));
                float lsum = 0.f, acc = 0.f;
                #pragma unroll
                for (int cc = 0; cc < 16; ++cc) {
                    float f = expf(gloadf(&apb[cc * 34]) - M);
                    lsum += gloadf(&apb[cc * 34 + 1]) * f;
                    acc  += gloadf(&apb[cc * 34 + 2 + tid]) * f;
                }
                os[tid] = acc / lsum;
            }
            __syncthreads();
            if (tid < 32) {
                int col = c * 32 + tid;
                float acc2 = 0.f;
                #pragma unroll
                for (int d = 0; d < DHD; ++d) acc2 += os[d] * ow_lds[d * 32 + tid];
                if (h == 0) acc2 += xs[col] + outb[(size_t)l * DMOD + col];
                atomicAdd(&u1_all[(size_t)l * DMOD + col], acc2);
            }
        }
        gsync(arr, epoch, tid, blk);

        // ---- stage 4: prefetch qkvw(l+1); ff (128 blocks) ----
        {
            if (l + 1 < LNUM && blk < 192) {
                int cb = blk >> 4, ks = blk & 15;
                const float* wb = qkvw + (size_t)(l + 1) * DMOD * 3 * DMOD
                                + (size_t)(ks * 32) * (3 * DMOD) + cb * 128;
                #pragma unroll
                for (int r = 0; r < 4; ++r) {
                    int f = (r * 256 + tid) * 4;
                    int row = f >> 7, col = f & 127;
                    gl_lds16(wb + (size_t)row * (3 * DMOD) + col, qw_lds + (r * 256 + wave * 64) * 4);
                }
            }
            if (blk < 128) {
                float* u1l = u1_all + (size_t)l * DMOD;
                float* u2l = u2_all + (size_t)l * DMOD;
                ln_into(u1l, ln1g + (size_t)l * DMOD, ln1b + (size_t)l * DMOD, xs, red8, tid);
                int jj = tid & 15, dg = tid >> 4;
                float acc = 0.f;
                #pragma unroll
                for (int i = 0; i < 32; ++i)
                    acc += xs[dg * 32 + i] * f1_lds[(dg * 32 + i) * 16 + jj];
                redt[tid] = acc;
                __syncthreads();
                for (int off = 128; off >= 16; off >>= 1) {
                    if (tid < off) redt[tid] += redt[tid + off];
                    __syncthreads();
                }
                if (tid < 16) hs[tid] = fmaxf(redt[tid] + ff1b[(size_t)l * FFD + blk * 16 + tid], 0.f);
                __syncthreads();
                #pragma unroll
                for (int half = 0; half < 2; ++half) {
                    int col = tid + half * 256;
                    float a2 = 0.f;
                    #pragma unroll
                    for (int j = 0; j < 16; ++j) a2 += hs[j] * f2_lds[j * 512 + col];
                    if (blk == 0) a2 += xs[col] + ff2b[(size_t)l * DMOD + col];
                    atomicAdd(&u2l[col], a2);
                }
            }
        }
        gsync(arr, epoch, tid, blk);
    }

    // ---- logits = LN(u2_last) @ pred_w; 256 blocks x 4 cols (+col 1024 on blk 255) ----
    {
        const float* u2L = u2_all + (size_t)(LNUM - 1) * DMOD;
        ln_into(u2L, ln2g + (size_t)(LNUM - 1) * DMOD, ln2b + (size_t)(LNUM - 1) * DMOD, xs, red8, tid);
        int cc = tid & 3, dg = tid >> 2;
        int col = blk * 4 + cc;
        const float* wp = predw + (size_t)(dg * 8) * VOC + col;
        float acc = 0.f;
        #pragma unroll
        for (int i = 0; i < 8; ++i) acc += xs[dg * 8 + i] * wp[(size_t)i * VOC];
        redt[tid] = acc;
        __syncthreads();
        for (int off = 128; off >= 4; off >>= 1) {
            if (tid < off) redt[tid] += redt[tid + off];
            __syncthreads();
        }
        if (tid < 4) gstoref(&logits[blk * 4 + tid], redt[tid]);
        if (blk == 255) {
            __syncthreads();
            float a2 = xs[tid * 2] * predw[(size_t)(tid * 2) * VOC + 1024]
                     + xs[tid * 2 + 1] * predw[(size_t)(tid * 2 + 1) * VOC + 1024];
            redt[tid] = a2;
            __syncthreads();
            for (int off = 128; off >= 1; off >>= 1) {
                if (tid < off) redt[tid] += redt[tid + off];
                __syncthreads();
            }
            if (tid == 0) gstoref(&logits[1024], redt[0]);
        }
    }
    gsync(arr, epoch, tid, blk);

    // ---- final: penalty + top-15 + softmax + noise argmax; block 0 only ----
    if (blk != 0) return;

    for (int i = tid; i < VOC; i += NTHR) { lg[i] = gloadf(&logits[i]); flagc[i] = 0; }
    __syncthreads();
    for (int j = tid; j < TYN; j += NTHR) flagc[y[j]] = 1;
    __syncthreads();
    for (int i = tid; i < VOC; i += NTHR) {
        if (flagc[i]) { float v = lg[i]; lg[i] = (v < 0.0f) ? v * 1.35f : v / 1.35f; }
    }
    __syncthreads();
    for (int i = tid; i < VOC; i += NTHR) sel[i] = lg[i];
    __syncthreads();

    float v0 = 0.f, v15 = 0.f;
    for (int k = 0; k < 15; ++k) {
        float bv = -INFINITY; int bi = VOC + 1;
        for (int i = tid; i < VOC; i += NTHR) {
            float v = sel[i];
            if (v > bv) { bv = v; bi = i; }
        }
        #pragma unroll
        for (int o = 32; o; o >>= 1) {
            float v2 = __shfl_xor(bv, o, 64);
            int i2 = __shfl_xor(bi, o, 64);
            if (v2 > bv || (v2 == bv && i2 < bi)) { bv = v2; bi = i2; }
        }
        if ((tid & 63) == 0) { rv[tid >> 6] = bv; ri[tid >> 6] = bi; }
        __syncthreads();
        if (tid == 0) {
            for (int w = 1; w < 4; ++w)
                if (rv[w] > rv[0] || (rv[w] == rv[0] && ri[w] < ri[0])) { rv[0] = rv[w]; ri[0] = ri[w]; }
            sel[ri[0]] = -INFINITY;
        }
        __syncthreads();
        if (k == 0)  v0  = rv[0];
        if (k == 14) v15 = rv[0];
        __syncthreads();
    }

    float se = 0.f;
    for (int i = tid; i < VOC; i += NTHR) {
        float v = lg[i];
        if (!(v < v15)) se += expf(v - v0);
    }
    se = wave_red_sum(se);
    if ((tid & 63) == 0) rv[tid >> 6] = se;
    __syncthreads();
    float total = rv[0] + rv[1] + rv[2] + rv[3];
    __syncthreads();

    float bv = -INFINITY; int bi = VOC + 1;
    for (int i = tid; i < VOC; i += NTHR) {
        float v = lg[i];
        float pr = (v < v15) ? 0.0f : expf(v - v0) / total;
        out[i] = pr;
        float r = pr / threefry_normal(i);
        if (r > bv || (r == bv && i < bi)) { bv = r; bi = i; }
    }
    #pragma unroll
    for (int o = 32; o; o >>= 1) {
        float v2 = __shfl_xor(bv, o, 64);
        int i2 = __shfl_xor(bi, o, 64);
        if (v2 > bv || (v2 == bv && i2 < bi)) { bv = v2; bi = i2; }
    }
    __syncthreads();
    if ((tid & 63) == 0) { rv[tid >> 6] = bv; ri[tid >> 6] = bi; }
    __syncthreads();
    if (tid == 0) {
        for (int w = 1; w < 4; ++w)
            if (rv[w] > rv[0] || (rv[w] == rv[0] && ri[w] < ri[0])) { rv[0] = rv[w]; ri[0] = ri[w]; }
        out[VOC] = (float)ri[0];
    }
}

// ---------------- host ----------------

extern "C" void kernel_launch(void* const* d_in, const int* in_sizes, int n_in,
                              void* d_out, int out_size, void* d_ws, size_t ws_size,
                              hipStream_t stream) {
    const int*   y      = (const int*)d_in[0];
    const float* kcache = (const float*)d_in[1];
    const float* vcache = (const float*)d_in[2];
    const float* tokemb = (const float*)d_in[4];
    const float* alpha  = (const float*)d_in[5];
    const float* qkvw   = (const float*)d_in[6];
    const float* qkvb   = (const float*)d_in[7];
    const float* outw   = (const float*)d_in[8];
    const float* outb   = (const float*)d_in[9];
    const float* ln1g   = (const float*)d_in[10];
    const float* ln1b   = (const float*)d_in[11];
    const float* ff1w   = (const float*)d_in[12];
    const float* ff1b   = (const float*)d_in[13];
    const float* ff2w   = (const float*)d_in[14];
    const float* ff2b   = (const float*)d_in[15];
    const float* ln2g   = (const float*)d_in[16];
    const float* ln2b   = (const float*)d_in[17];
    const float* predw  = (const float*)d_in[18];
    float* outp = (float*)d_out;
    float* wsf  = (float*)d_ws;

    // zero: arrive slots (4096) + atomic-accumulated qkv/u1/u2 (61440)
    const int ZN = 4096 + LNUM * 3 * DMOD + LNUM * DMOD + LNUM * DMOD;  // 65536
    zero_kernel<<<(ZN + 255) / 256, 256, 0, stream>>>(wsf, ZN);

    void* args[] = {
        (void*)&y, (void*)&kcache, (void*)&vcache, (void*)&tokemb, (void*)&alpha,
        (void*)&qkvw, (void*)&qkvb, (void*)&outw, (void*)&outb,
        (void*)&ln1g, (void*)&ln1b, (void*)&ff1w, (void*)&ff1b,
        (void*)&ff2w, (void*)&ff2b, (void*)&ln2g, (void*)&ln2b,
        (void*)&predw, (void*)&outp, (void*)&wsf
    };
    hipLaunchCooperativeKernel((const void*)decode_kernel, dim3(NBLK), dim3(NTHR),
                               args, 0, stream);
}

// Round 4
// 860.355 us; speedup vs baseline: 1.2667x; 1.2667x over previous
//
#include <hip/hip_runtime.h>
#include <math.h>

// Text2SemanticDecoder single-token decode, MI355X round 5.
// R3 (619us): 4-stage coop kernel, two-hop barrier, cold weight loads.
// R4 (772us, FAILED): LDS weight prefetch — global_load_lds forces vmcnt(0)
// drain before s_barrier => prefetch serialized INTO barrier arrival; plus
// every-thread polling storm. Lesson: prefetch must target REGISTERS (waited
// only at use), and polling must be one wave per block.
// R5: (a) cross-barrier REGISTER prefetch of next-stage weight slices
//     (KV, outw, ff1, qkvw(l+1), predw) issued right after arrival store;
//     (b) one-hop barrier, wave-0-only poll of 4 slots/lane, __all exit;
//     (c) fused LN sum/sumsq reduce; xs persisted stage1->stage3;
//     (d) u2 atomic depth 128->16 via 8 partial arrays; in-kernel zeroing;
//     (e) register-held top-15 in final stage.

#define LNUM 24
#define TPOS 2048
#define DMOD 512
#define HNUM 16
#define VOC  1025
#define TYN  512
#define FFD  2048
#define DHD  32
#define NBLK 256
#define NTHR 256

#define INV_SQRT_DH 0.17677669529663687f

// ---------------- helpers ----------------

__device__ __forceinline__ unsigned rotl32(unsigned x, int d) {
    return (x << d) | (x >> (32 - d));
}

// threefry2x32, PARTITIONABLE scheme: key=(0,42), ctr=(0,i), bits=o0^o1
__device__ float threefry_normal(int i) {
    unsigned c0 = 0u;
    unsigned c1 = (unsigned)i;
    unsigned ks[3];
    ks[0] = 0u; ks[1] = 42u; ks[2] = 0x1BD11BDAu ^ ks[0] ^ ks[1];
    unsigned x0 = c0 + ks[0];
    unsigned x1 = c1 + ks[1];
    const int r0[4] = {13, 15, 26, 6};
    const int r1[4] = {17, 29, 16, 24};
    #pragma unroll
    for (int g = 0; g < 5; ++g) {
        const int* rr = (g & 1) ? r1 : r0;
        #pragma unroll
        for (int j = 0; j < 4; ++j) {
            x0 += x1; x1 = rotl32(x1, rr[j]); x1 ^= x0;
        }
        x0 += ks[(g + 1) % 3];
        x1 += ks[(g + 2) % 3] + (unsigned)(g + 1);
    }
    unsigned bits = x0 ^ x1;
    float u01 = __uint_as_float((bits >> 9) | 0x3f800000u) - 1.0f;
    const float lo = -0.99999994f;
    float u = u01 * (1.0f - lo) + lo;
    u = fmaxf(lo, u);
    float w = -log1pf(-u * u);
    float pp;
    if (w < 5.0f) {
        w = w - 2.5f;
        pp = 2.81022636e-08f;
        pp = fmaf(pp, w, 3.43273939e-07f);
        pp = fmaf(pp, w, -3.5233877e-06f);
        pp = fmaf(pp, w, -4.39150654e-06f);
        pp = fmaf(pp, w, 0.00021858087f);
        pp = fmaf(pp, w, -0.00125372503f);
        pp = fmaf(pp, w, -0.00417768164f);
        pp = fmaf(pp, w, 0.246640727f);
        pp = fmaf(pp, w, 1.50140941f);
    } else {
        w = sqrtf(w) - 3.0f;
        pp = -0.000200214257f;
        pp = fmaf(pp, w, 0.000100950558f);
        pp = fmaf(pp, w, 0.00134934322f);
        pp = fmaf(pp, w, -0.00367342844f);
        pp = fmaf(pp, w, 0.00573950773f);
        pp = fmaf(pp, w, -0.0076224613f);
        pp = fmaf(pp, w, 0.00943887047f);
        pp = fmaf(pp, w, 1.00167406f);
        pp = fmaf(pp, w, 2.83297682f);
    }
    return 1.4142135623730951f * pp * u;  // sqrt(2)*erfinv(u)
}

__global__ void zero_kernel(float* p, int n) {
    int i = blockIdx.x * blockDim.x + threadIdx.x;
    if (i < n) p[i] = 0.0f;
}

__device__ __forceinline__ float wave_red_sum(float v) {
    #pragma unroll
    for (int o = 32; o; o >>= 1) v += __shfl_xor(v, o, 64);
    return v;
}
__device__ __forceinline__ float block_sum(float v, float* red8, int tid) {
    v = wave_red_sum(v);
    __syncthreads();
    if ((tid & 63) == 0) red8[tid >> 6] = v;
    __syncthreads();
    return red8[0] + red8[1] + red8[2] + red8[3];
}
__device__ __forceinline__ float block_max(float v, float* red8, int tid) {
    #pragma unroll
    for (int o = 32; o; o >>= 1) v = fmaxf(v, __shfl_xor(v, o, 64));
    __syncthreads();
    if ((tid & 63) == 0) red8[tid >> 6] = v;
    __syncthreads();
    return fmaxf(fmaxf(red8[0], red8[1]), fmaxf(red8[2], red8[3]));
}

// agent-scope (cross-XCD coherent) ops
__device__ __forceinline__ float gloadf(const float* p) {
    return __hip_atomic_load((float*)p, __ATOMIC_RELAXED, __HIP_MEMORY_SCOPE_AGENT);
}
__device__ __forceinline__ void gstoref(float* p, float v) {
    __hip_atomic_store(p, v, __ATOMIC_RELAXED, __HIP_MEMORY_SCOPE_AGENT);
}
__device__ __forceinline__ unsigned gloadu(const unsigned* p) {
    return __hip_atomic_load((unsigned*)p, __ATOMIC_RELAXED, __HIP_MEMORY_SCOPE_AGENT);
}
__device__ __forceinline__ void gstoreu(unsigned* p, unsigned v) {
    __hip_atomic_store(p, v, __ATOMIC_RELAXED, __HIP_MEMORY_SCOPE_AGENT);
}

// barrier phase 1: entry sync (drains all waves' stores) + arrival store
#define GSYNC_ARRIVE()                                            \
    do { __syncthreads(); ++epoch;                                \
         if (tid == 0) gstoreu(&arr[blk * 4], epoch); } while (0)

// barrier phase 2: wave-0 poll (4 slots per lane), then block release
__device__ __forceinline__ void gsync_wait(const unsigned* arr, unsigned epoch, int tid) {
    if (tid < 64) {
        for (;;) {
            unsigned a0 = gloadu(&arr[tid * 4]);
            unsigned a1 = gloadu(&arr[(tid + 64) * 4]);
            unsigned a2 = gloadu(&arr[(tid + 128) * 4]);
            unsigned a3 = gloadu(&arr[(tid + 192) * 4]);
            unsigned m01 = a0 < a1 ? a0 : a1;
            unsigned m23 = a2 < a3 ? a2 : a3;
            unsigned mn = m01 < m23 ? m01 : m23;
            if (__all(mn >= epoch)) break;
            __builtin_amdgcn_s_sleep(1);
        }
    }
    __syncthreads();
}

// fused LN: inputs a = u[tid], c = u[tid+256]; writes xs[512]
__device__ __forceinline__ void ln_finish(float a, float c, const float* __restrict__ g,
                                          const float* __restrict__ b, float* xs,
                                          float* red8, int tid) {
    float s1 = a + c, s2 = a * a + c * c;
    #pragma unroll
    for (int o = 32; o; o >>= 1) { s1 += __shfl_xor(s1, o, 64); s2 += __shfl_xor(s2, o, 64); }
    __syncthreads();
    if ((tid & 63) == 0) { red8[(tid >> 6) * 2] = s1; red8[(tid >> 6) * 2 + 1] = s2; }
    __syncthreads();
    s1 = red8[0] + red8[2] + red8[4] + red8[6];
    s2 = red8[1] + red8[3] + red8[5] + red8[7];
    float mu = s1 * (1.0f / DMOD);
    float var = s2 * (1.0f / DMOD) - mu * mu;
    float rstd = rsqrtf(var + 1e-5f);
    xs[tid]       = (a - mu) * rstd * g[tid] + b[tid];
    xs[tid + 256] = (c - mu) * rstd * g[tid + 256] + b[tid + 256];
    __syncthreads();
}

__device__ __forceinline__ void ln_u1(const float* __restrict__ u, const float* __restrict__ g,
                                      const float* __restrict__ b, float* xs, float* red8, int tid) {
    float a = gloadf(u + tid), c = gloadf(u + tid + 256);
    ln_finish(a, c, g, b, xs, red8, tid);
}

// LN over u2 stored as 8 partial arrays (stride 512)
__device__ __forceinline__ void ln8(const float* __restrict__ up, const float* __restrict__ g,
                                    const float* __restrict__ b, float* xs, float* red8, int tid) {
    float a = 0.f, c = 0.f;
    #pragma unroll
    for (int p = 0; p < 8; ++p) {
        a += gloadf(up + p * 512 + tid);
        c += gloadf(up + p * 512 + tid + 256);
    }
    ln_finish(a, c, g, b, xs, red8, tid);
}

// layer-0 input: tok_emb[last] + alpha*pe(pos=512)
__device__ __forceinline__ void x0_into(const int* __restrict__ y, const float* __restrict__ tokemb,
                                        const float* __restrict__ alpha, float* xs, int tid) {
    int tok = y[TYN - 1];
    #pragma unroll
    for (int r = 0; r < 2; ++r) {
        int d = tid + r * 256;
        float e = tokemb[(size_t)tok * DMOD + d];
        int base = d & ~1;
        float div = expf(-(float)base * (logf(10000.0f) / (float)DMOD));
        float ang = 512.0f * div;
        float pe = (d & 1) ? cosf(ang) : sinf(ang);
        xs[d] = e + alpha[0] * pe;
    }
    __syncthreads();
}

// ---------------- the persistent kernel ----------------

__global__ __launch_bounds__(NTHR, 1) void decode_kernel(
    const int* __restrict__ y, const float* __restrict__ kcache, const float* __restrict__ vcache,
    const float* __restrict__ tokemb, const float* __restrict__ alpha,
    const float* __restrict__ qkvw, const float* __restrict__ qkvbias,
    const float* __restrict__ outw, const float* __restrict__ outb,
    const float* __restrict__ ln1g, const float* __restrict__ ln1b,
    const float* __restrict__ ff1w, const float* __restrict__ ff1b,
    const float* __restrict__ ff2w, const float* __restrict__ ff2b,
    const float* __restrict__ ln2g, const float* __restrict__ ln2b,
    const float* __restrict__ predw, float* __restrict__ out, float* ws)
{
    __shared__ float xs[DMOD];        // persists stage1 -> stage3 (residual)
    __shared__ float red8[8];
    __shared__ float ps[136];
    __shared__ float vred[NTHR];
    __shared__ float qs[DHD];
    __shared__ float os[DHD];
    __shared__ float hs[16];
    __shared__ float redt[NTHR];
    // final stage
    __shared__ float lg[VOC];
    __shared__ unsigned char flagc[VOC];
    __shared__ float rv[4];
    __shared__ int   ri[4];

    const int tid = threadIdx.x, blk = blockIdx.x;
    const int h = blk >> 4, c = blk & 15;   // stage1: cb=h (blk<192), ks=c

    // ws layout (floats):
    //   [0,4096)   arrive slots (256 x 16B stride, only [0,1024) used)
    //   qkv[24*1536] | u1[24*512] | u2p[24*8*512] | attnp[16*16*34] | logits[1025]
    unsigned* arr   = (unsigned*)ws;
    float* qkv_all  = ws + 4096;
    float* u1_all   = qkv_all + LNUM * 3 * DMOD;
    float* u2p_all  = u1_all + LNUM * DMOD;
    float* attnp    = u2p_all + LNUM * 8 * DMOD;
    float* logits   = attnp + HNUM * 16 * 34;
    unsigned epoch  = 0;

    float* kout = out + 1026;
    float* vout = out + 1026 + (size_t)LNUM * DMOD;

    float qwr[16];   // next qkv weight slice (assigned boundary 4->1 / prologue)
    float pwr[8];    // pred_w slice (assigned at l==23 boundary)

    // prologue: register-prefetch layer-0 qkvw slice
    if (blk < 192) {
        const int cc = tid & 127, rg = tid >> 7;
        const float* wp = qkvw + (size_t)(c * 32 + rg * 16) * (3 * DMOD) + h * 128 + cc;
        #pragma unroll
        for (int i = 0; i < 16; ++i) qwr[i] = wp[(size_t)i * (3 * DMOD)];
    }

    for (int l = 0; l < LNUM; ++l) {
        float* qkv_l = qkv_all + (size_t)l * 3 * DMOD;
        float* u1_l  = u1_all  + (size_t)l * DMOD;
        float* u2p_l = u2p_all + (size_t)l * 8 * DMOD;
        float kr[16], vr[16], wr4[4], f1r[32];

        // ---- stage 1: qkv = LN(x_prev) @ W + b (blocks<192); others zero u1/u2p ----
        if (blk < 192) {
            if (l == 0) x0_into(y, tokemb, alpha, xs, tid);
            else        ln8(u2p_all + (size_t)(l - 1) * 8 * DMOD,
                            ln2g + (size_t)(l - 1) * DMOD, ln2b + (size_t)(l - 1) * DMOD,
                            xs, red8, tid);
            const int cc = tid & 127, rg = tid >> 7;
            const int col = h * 128 + cc;
            float acc = 0.f;
            #pragma unroll
            for (int i = 0; i < 16; ++i) acc += xs[c * 32 + rg * 16 + i] * qwr[i];
            if (c == 0 && tid < 128) acc += qkvbias[(size_t)l * 3 * DMOD + col];
            atomicAdd(&qkv_l[col], acc);
        } else {
            const int zi = blk - 192;
            if (tid < 8)  gstoref(u1_l + zi * 8 + tid, 0.f);
            if (tid < 64) gstoref(u2p_l + zi * 64 + tid, 0.f);
        }
        GSYNC_ARRIVE();
        {   // prefetch K/V chunk for stage 2 (registers)
            const int d = tid & 31, pg = tid >> 5;
            const float* kp = kcache + ((size_t)l * TPOS + c * 128 + pg * 16) * DMOD + h * DHD + d;
            const float* vp = vcache + ((size_t)l * TPOS + c * 128 + pg * 16) * DMOD + h * DHD + d;
            #pragma unroll
            for (int i = 0; i < 16; ++i) kr[i] = kp[(size_t)i * DMOD];
            #pragma unroll
            for (int i = 0; i < 16; ++i) vr[i] = vp[(size_t)i * DMOD];
        }
        gsync_wait(arr, epoch, tid);

        // ---- stage 2: attention partials (all 256 blocks = 16h x 16c) ----
        {
            if (tid < DHD) qs[tid] = gloadf(&qkv_l[h * DHD + tid]);
            __syncthreads();
            const int d = tid & 31, pg = tid >> 5;
            #pragma unroll
            for (int i = 0; i < 16; ++i) {
                float prod = qs[d] * kr[i];
                #pragma unroll
                for (int o = 16; o; o >>= 1) prod += __shfl_xor(prod, o, 64);
                if (d == 0) ps[pg * 16 + i] = prod * INV_SQRT_DH;
            }
            if (c == 15 && tid < 32) {   // new-token score
                float prod = qs[tid] * gloadf(&qkv_l[DMOD + h * DHD + tid]);
                #pragma unroll
                for (int o = 16; o; o >>= 1) prod += __shfl_xor(prod, o, 64);
                if (tid == 0) ps[128] = prod * INV_SQRT_DH;
            }
            const int limit = (c == 15) ? 129 : 128;
            float sv = -INFINITY;
            float m, lsum, pe;
            __syncthreads();
            if (tid < limit) sv = ps[tid];
            m = block_max(sv, red8, tid);
            pe = expf(sv - m);
            if (tid < limit) ps[tid] = pe;
            lsum = block_sum((tid < limit) ? pe : 0.f, red8, tid);
            float acc = 0.f;
            #pragma unroll
            for (int i = 0; i < 16; ++i) acc += ps[pg * 16 + i] * vr[i];
            if (c == 15 && pg == 0) acc += ps[128] * gloadf(&qkv_l[2 * DMOD + h * DHD + d]);
            vred[tid] = acc;
            __syncthreads();
            float* ap = attnp + (size_t)(h * 16 + c) * 34;
            if (tid < DHD) {
                float a = 0.f;
                #pragma unroll
                for (int g = 0; g < 8; ++g) a += vred[g * DHD + tid];
                gstoref(&ap[2 + tid], a);
            }
            if (tid == 0) { gstoref(&ap[0], m); gstoref(&ap[1], lsum); }
            if (c == 0 && tid < DHD) {
                kout[(size_t)l * DMOD + h * DHD + tid] = gloadf(&qkv_l[DMOD + h * DHD + tid]);
                vout[(size_t)l * DMOD + h * DHD + tid] = gloadf(&qkv_l[2 * DMOD + h * DHD + tid]);
            }
        }
        GSYNC_ARRIVE();
        {   // prefetch out_w slice for stage 3
            const int co = tid & 31, ro = tid >> 5;
            const float* wp = outw + (size_t)l * DMOD * DMOD + (size_t)(h * DHD + ro * 4) * DMOD
                            + c * 32 + co;
            #pragma unroll
            for (int i = 0; i < 4; ++i) wr4[i] = wp[(size_t)i * DMOD];
        }
        gsync_wait(arr, epoch, tid);

        // ---- stage 3: combine + out-proj + residual -> u1 (16h x 16colgrp) ----
        {
            const float* apb = attnp + (size_t)(h * 16) * 34;
            if (tid < DHD) {
                float M = -INFINITY;
                #pragma unroll
                for (int cc = 0; cc < 16; ++cc) M = fmaxf(M, gloadf(&apb[cc * 34]));
                float lsum = 0.f, acc = 0.f;
                #pragma unroll
                for (int cc = 0; cc < 16; ++cc) {
                    float f = expf(gloadf(&apb[cc * 34]) - M);
                    lsum += gloadf(&apb[cc * 34 + 1]) * f;
                    acc  += gloadf(&apb[cc * 34 + 2 + tid]) * f;
                }
                os[tid] = acc / lsum;
            }
            __syncthreads();
            const int co = tid & 31, ro = tid >> 5;
            float pacc = 0.f;
            #pragma unroll
            for (int i = 0; i < 4; ++i) pacc += os[ro * 4 + i] * wr4[i];
            vred[tid] = pacc;
            __syncthreads();
            if (tid < 32) {
                float s = 0.f;
                #pragma unroll
                for (int g = 0; g < 8; ++g) s += vred[g * 32 + tid];
                int col = c * 32 + tid;
                if (h == 0) s += xs[col] + outb[(size_t)l * DMOD + col];  // xs persisted
                atomicAdd(&u1_l[col], s);
            }
            (void)co;
        }
        GSYNC_ARRIVE();
        if (blk < 128) {   // prefetch ff1 slice for stage 4
            const int jj = tid & 15, dg = tid >> 4;
            const float* fp = ff1w + (size_t)l * DMOD * FFD + (size_t)(dg * 32) * FFD + blk * 16 + jj;
            #pragma unroll
            for (int i = 0; i < 32; ++i) f1r[i] = fp[(size_t)i * FFD];
        }
        gsync_wait(arr, epoch, tid);

        // ---- stage 4: ff (blocks<128, 16 hidden each); 128-191 zero next qkv ----
        if (blk < 128) {
            // early-issue ff2 slice into registers (consumed after ff1)
            float f2r[32];
            {
                const float* fp = ff2w + (size_t)l * FFD * DMOD + (size_t)(blk * 16) * DMOD + tid * 2;
                #pragma unroll
                for (int j = 0; j < 16; ++j) {
                    f2r[2 * j]     = fp[(size_t)j * DMOD];
                    f2r[2 * j + 1] = fp[(size_t)j * DMOD + 1];
                }
            }
            ln_u1(u1_l, ln1g + (size_t)l * DMOD, ln1b + (size_t)l * DMOD, xs, red8, tid);
            const int jj = tid & 15, dg = tid >> 4;
            float acc = 0.f;
            #pragma unroll
            for (int i = 0; i < 32; ++i) acc += xs[dg * 32 + i] * f1r[i];
            redt[tid] = acc;
            __syncthreads();
            for (int off = 128; off >= 16; off >>= 1) {
                if (tid < off) redt[tid] += redt[tid + off];
                __syncthreads();
            }
            if (tid < 16) hs[tid] = fmaxf(redt[tid] + ff1b[(size_t)l * FFD + blk * 16 + tid], 0.f);
            __syncthreads();
            #pragma unroll
            for (int p = 0; p < 2; ++p) {
                int col = tid * 2 + p;
                float a2 = 0.f;
                #pragma unroll
                for (int j = 0; j < 16; ++j) a2 += hs[j] * f2r[2 * j + p];
                if (blk == 0) a2 += xs[col] + ff2b[(size_t)l * DMOD + col];
                atomicAdd(&u2p_l[(blk & 7) * DMOD + col], a2);
            }
            (void)jj;
        } else if (blk < 192 && l + 1 < LNUM) {
            if (tid < 24) gstoref(qkv_all + (size_t)(l + 1) * 3 * DMOD + (blk - 128) * 24 + tid, 0.f);
        }
        GSYNC_ARRIVE();
        if (l + 1 < LNUM) {
            if (blk < 192) {   // prefetch next layer's qkvw slice
                const int cc = tid & 127, rg = tid >> 7;
                const float* wp = qkvw + (size_t)(l + 1) * DMOD * 3 * DMOD
                                + (size_t)(c * 32 + rg * 16) * (3 * DMOD) + h * 128 + cc;
                #pragma unroll
                for (int i = 0; i < 16; ++i) qwr[i] = wp[(size_t)i * (3 * DMOD)];
            }
        } else {               // prefetch pred_w slice for logits
            const int cc = tid & 3, dg = tid >> 2;
            const float* pp = predw + (size_t)(dg * 8) * VOC + blk * 4 + cc;
            #pragma unroll
            for (int i = 0; i < 8; ++i) pwr[i] = pp[(size_t)i * VOC];
        }
        gsync_wait(arr, epoch, tid);
    }

    // ---- logits = LN(u2_last) @ pred_w; 256 blocks x 4 cols (+col1024 on blk255) ----
    {
        ln8(u2p_all + (size_t)(LNUM - 1) * 8 * DMOD,
            ln2g + (size_t)(LNUM - 1) * DMOD, ln2b + (size_t)(LNUM - 1) * DMOD, xs, red8, tid);
        const int cc = tid & 3, dg = tid >> 2;
        float acc = 0.f;
        #pragma unroll
        for (int i = 0; i < 8; ++i) acc += xs[dg * 8 + i] * pwr[i];
        redt[tid] = acc;
        __syncthreads();
        for (int off = 128; off >= 4; off >>= 1) {
            if (tid < off) redt[tid] += redt[tid + off];
            __syncthreads();
        }
        if (tid < 4) gstoref(&logits[blk * 4 + tid], redt[tid]);
        if (blk == 255) {
            __syncthreads();
            float a2 = xs[tid * 2] * predw[(size_t)(tid * 2) * VOC + 1024]
                     + xs[tid * 2 + 1] * predw[(size_t)(tid * 2 + 1) * VOC + 1024];
            redt[tid] = a2;
            __syncthreads();
            for (int off = 128; off >= 1; off >>= 1) {
                if (tid < off) redt[tid] += redt[tid + off];
                __syncthreads();
            }
            if (tid == 0) gstoref(&logits[1024], redt[0]);
        }
        (void)cc;
    }
    GSYNC_ARRIVE();
    gsync_wait(arr, epoch, tid);

    // ---- final: penalty + top-15 + softmax + noise argmax; block 0 only ----
    if (blk != 0) return;

    for (int i = tid; i < VOC; i += NTHR) { lg[i] = gloadf(&logits[i]); flagc[i] = 0; }
    __syncthreads();
    for (int j = tid; j < TYN; j += NTHR) flagc[y[j]] = 1;
    __syncthreads();
    for (int i = tid; i < VOC; i += NTHR) {
        if (flagc[i]) { float v = lg[i]; lg[i] = (v < 0.0f) ? v * 1.35f : v / 1.35f; }
    }
    __syncthreads();

    // register-held candidates: thread tid owns indices tid, tid+256, ...
    float lv[5]; int li[5];
    #pragma unroll
    for (int k = 0; k < 5; ++k) {
        int idx = tid + k * 256;
        bool ok = idx < VOC;
        lv[k] = ok ? lg[idx] : -INFINITY;
        li[k] = ok ? idx : (1 << 30);
    }
    float v0 = 0.f, v15 = 0.f;
    for (int k = 0; k < 15; ++k) {
        float bv = -INFINITY; int bi = (1 << 30);
        #pragma unroll
        for (int j = 0; j < 5; ++j)
            if (lv[j] > bv || (lv[j] == bv && li[j] < bi)) { bv = lv[j]; bi = li[j]; }
        #pragma unroll
        for (int o = 32; o; o >>= 1) {
            float v2 = __shfl_xor(bv, o, 64);
            int i2 = __shfl_xor(bi, o, 64);
            if (v2 > bv || (v2 == bv && i2 < bi)) { bv = v2; bi = i2; }
        }
        if ((tid & 63) == 0) { rv[tid >> 6] = bv; ri[tid >> 6] = bi; }
        __syncthreads();
        float fbv = rv[0]; int fbi = ri[0];
        #pragma unroll
        for (int w = 1; w < 4; ++w) {
            float v2 = rv[w]; int i2 = ri[w];
            if (v2 > fbv || (v2 == fbv && i2 < fbi)) { fbv = v2; fbi = i2; }
        }
        if (k == 0)  v0  = fbv;
        if (k == 14) v15 = fbv;
        #pragma unroll
        for (int j = 0; j < 5; ++j) if (li[j] == fbi) lv[j] = -INFINITY;
        __syncthreads();
    }

    float se = 0.f;
    for (int i = tid; i < VOC; i += NTHR) {
        float v = lg[i];
        if (!(v < v15)) se += expf(v - v0);
    }
    se = wave_red_sum(se);
    __syncthreads();
    if ((tid & 63) == 0) rv[tid >> 6] = se;
    __syncthreads();
    float total = rv[0] + rv[1] + rv[2] + rv[3];
    __syncthreads();

    float bv = -INFINITY; int bi = (1 << 30);
    for (int i = tid; i < VOC; i += NTHR) {
        float v = lg[i];
        float pr = (v < v15) ? 0.0f : expf(v - v0) / total;
        out[i] = pr;
        float r = pr / threefry_normal(i);
        if (r > bv || (r == bv && i < bi)) { bv = r; bi = i; }
    }
    #pragma unroll
    for (int o = 32; o; o >>= 1) {
        float v2 = __shfl_xor(bv, o, 64);
        int i2 = __shfl_xor(bi, o, 64);
        if (v2 > bv || (v2 == bv && i2 < bi)) { bv = v2; bi = i2; }
    }
    if ((tid & 63) == 0) { rv[tid >> 6] = bv; ri[tid >> 6] = bi; }
    __syncthreads();
    if (tid == 0) {
        for (int w = 1; w < 4; ++w)
            if (rv[w] > rv[0] || (rv[w] == rv[0] && ri[w] < ri[0])) { rv[0] = rv[w]; ri[0] = ri[w]; }
        out[VOC] = (float)ri[0];
    }
}

// ---------------- host ----------------

extern "C" void kernel_launch(void* const* d_in, const int* in_sizes, int n_in,
                              void* d_out, int out_size, void* d_ws, size_t ws_size,
                              hipStream_t stream) {
    const int*   y      = (const int*)d_in[0];
    const float* kcache = (const float*)d_in[1];
    const float* vcache = (const float*)d_in[2];
    const float* tokemb = (const float*)d_in[4];
    const float* alpha  = (const float*)d_in[5];
    const float* qkvw   = (const float*)d_in[6];
    const float* qkvb   = (const float*)d_in[7];
    const float* outw   = (const float*)d_in[8];
    const float* outb   = (const float*)d_in[9];
    const float* ln1g   = (const float*)d_in[10];
    const float* ln1b   = (const float*)d_in[11];
    const float* ff1w   = (const float*)d_in[12];
    const float* ff1b   = (const float*)d_in[13];
    const float* ff2w   = (const float*)d_in[14];
    const float* ff2b   = (const float*)d_in[15];
    const float* ln2g   = (const float*)d_in[16];
    const float* ln2b   = (const float*)d_in[17];
    const float* predw  = (const float*)d_in[18];
    float* outp = (float*)d_out;
    float* wsf  = (float*)d_ws;

    // zero: arrive slots region (4096 floats incl. padding) + qkv layer 0 (1536).
    // u1[l]/u2p[l] zeroed in-kernel by idle blocks in stage 1 of layer l;
    // qkv[l+1] zeroed by idle blocks in stage 4 of layer l.
    zero_kernel<<<(5632 + 255) / 256, 256, 0, stream>>>(wsf, 5632);

    void* args[] = {
        (void*)&y, (void*)&kcache, (void*)&vcache, (void*)&tokemb, (void*)&alpha,
        (void*)&qkvw, (void*)&qkvb, (void*)&outw, (void*)&outb,
        (void*)&ln1g, (void*)&ln1b, (void*)&ff1w, (void*)&ff1b,
        (void*)&ff2w, (void*)&ff2b, (void*)&ln2g, (void*)&ln2b,
        (void*)&predw, (void*)&outp, (void*)&wsf
    };
    hipLaunchCooperativeKernel((const void*)decode_kernel, dim3(NBLK), dim3(NTHR),
                               args, 0, stream);
}